// Round 5
// baseline (113.685 us; speedup 1.0000x reference)
//
#include <hip/hip_runtime.h>
#include <math.h>

// Problem constants (from reference setup_inputs)
static constexpr int B_TOTAL = 131072;
static constexpr int M_MOD   = 14;    // NB_MOD_MAX + 2
static constexpr int C_DIM   = 128;   // CONCEPT_N

// ---------- DPP helpers: cross-lane moves fused into VALU ops ----------
// dpp_ctrl must be an IR constant -> template parameter.
template <int CTRL>
__device__ __forceinline__ float dpp_mov(float x) {
    return __int_as_float(__builtin_amdgcn_update_dpp(
        0, __float_as_int(x), CTRL, 0xF, 0xF, true));
}
// Full 16-lane sum in every lane. 16 lanes = one DPP row:
// row_ror:8 == xor8, row_ror:4 == xor4 (after the ror8 stage each half is
// symmetric, so ror==xor for the remaining stages), quad_perm for xor2/xor1.
#define ROW_SUM(x)                                                             \
    do {                                                                       \
        x += dpp_mov<0x128>(x); /* row_ror:8 */                                \
        x += dpp_mov<0x124>(x); /* row_ror:4 */                                \
        x += dpp_mov<0x04E>(x); /* quad_perm(2,3,0,1) = xor 2 */               \
        x += dpp_mov<0x0B1>(x); /* quad_perm(1,0,3,2) = xor 1 */               \
    } while (0)
#define ROW_MIN(x)                                                             \
    do {                                                                       \
        x = fminf(x, dpp_mov<0x128>(x));                                       \
        x = fminf(x, dpp_mov<0x124>(x));                                       \
        x = fminf(x, dpp_mov<0x04E>(x));                                       \
        x = fminf(x, dpp_mov<0x0B1>(x));                                       \
    } while (0)

// ---------- Prologue: G[c] = W[c] W[c]^T (3x3 Gram, 6 uniques) ----------
// One 64-lane wave per concept; lane owns 2 columns. Output padded to 8
// floats/concept in d_ws (4 KB total).
__global__ __launch_bounds__(64) void gram_kernel(
    const float* __restrict__ W, float* __restrict__ g)
{
    const int c = blockIdx.x;
    const int l = threadIdx.x;
    const float2* wp = (const float2*)(W + (size_t)c * 3 * C_DIM);
    const float2 a0 = wp[l], a1 = wp[64 + l], a2 = wp[128 + l];
    float g00 = a0.x * a0.x + a0.y * a0.y;
    float g01 = a0.x * a1.x + a0.y * a1.y;
    float g02 = a0.x * a2.x + a0.y * a2.y;
    float g11 = a1.x * a1.x + a1.y * a1.y;
    float g12 = a1.x * a2.x + a1.y * a2.y;
    float g22 = a2.x * a2.x + a2.y * a2.y;
#pragma unroll
    for (int off = 32; off; off >>= 1) {
        g00 += __shfl_xor(g00, off, 64);
        g01 += __shfl_xor(g01, off, 64);
        g02 += __shfl_xor(g02, off, 64);
        g11 += __shfl_xor(g11, off, 64);
        g12 += __shfl_xor(g12, off, 64);
        g22 += __shfl_xor(g22, off, 64);
    }
    if (l == 0) {
        float* o = g + c * 8;
        o[0] = g00; o[1] = g01; o[2] = g02;
        o[3] = g11; o[4] = g12; o[5] = g22;
        o[6] = 0.f; o[7] = 0.f;
    }
}

// ---------- Main: one 16-lane group per element, 4 elements/wave ----------
// argmin_j ||u - im_j||^2 = argmin_j ( P_j^T G P_j - 2 P_j . v ),
// v = W_t u, G from d_ws. Lane s owns 8 concept cols; after the v-reduce,
// lane s scores modality j = s+1; DPP min + ballot/ctz gives first-index
// argmin (jnp tiebreak).
__global__ __launch_bounds__(256) void impact_kernel(
    const int*   __restrict__ user_ids,
    const int*   __restrict__ item_ids,
    const int*   __restrict__ concept_ids,
    const float* __restrict__ users_emb,   // (USER_N, 128)
    const float* __restrict__ item_resp,   // (ITEM_N * 14, 3)
    const float* __restrict__ W,           // (128, 3, 128)
    const int*   __restrict__ nb_mod,      // (ITEM_N,)
    const float* __restrict__ gram,        // (128, 8) in d_ws
    float*       __restrict__ out)         // (B,)
{
    const int s = threadIdx.x & 15;                     // sublane in group
    const int b = blockIdx.x * 16 + (threadIdx.x >> 4); // element id

    const int uid = user_ids[b];
    const int iid = item_ids[b];
    const int cid = concept_ids[b];
    const int nb  = nb_mod[iid];

    // u row: 2 x float4 per lane (256 B coalesced runs per group).
    const float4* up = (const float4*)(users_emb + (size_t)uid * C_DIM);
    const float4 uA = up[s], uB = up[s + 16];
    // W_t = W[cid]: 3 rows x 512 B (table is 196 KB -> L2-resident).
    const float4* wp = (const float4*)(W + (size_t)cid * 3 * C_DIM);
    const float4 w0a = wp[s],      w0b = wp[16 + s];
    const float4 w1a = wp[32 + s], w1b = wp[48 + s];
    const float4 w2a = wp[64 + s], w2b = wp[80 + s];
    // Gram for this concept (group-uniform, 4 KB table -> L1-hot).
    const float4 gA = ((const float4*)(gram + cid * 8))[0];
    const float4 gB = ((const float4*)(gram + cid * 8))[1];
    // Item response row for this lane's modality j = s+1.
    const float* pj = item_resp + ((size_t)iid * M_MOD + (s < 12 ? s + 1 : 1)) * 3;
    const float p0 = pj[0], p1 = pj[1], p2 = pj[2];

    // v = W_t u over this lane's 8 columns.
    float v0 = 0.f, v1 = 0.f, v2 = 0.f;
#define COL(uc, a0, a1, a2)                                                    \
    do {                                                                       \
        v0 = fmaf((a0), (uc), v0);                                             \
        v1 = fmaf((a1), (uc), v1);                                             \
        v2 = fmaf((a2), (uc), v2);                                             \
    } while (0)
    COL(uA.x, w0a.x, w1a.x, w2a.x);
    COL(uA.y, w0a.y, w1a.y, w2a.y);
    COL(uA.z, w0a.z, w1a.z, w2a.z);
    COL(uA.w, w0a.w, w1a.w, w2a.w);
    COL(uB.x, w0b.x, w1b.x, w2b.x);
    COL(uB.y, w0b.y, w1b.y, w2b.y);
    COL(uB.z, w0b.z, w1b.z, w2b.z);
    COL(uB.w, w0b.w, w1b.w, w2b.w);
#undef COL
    ROW_SUM(v0);
    ROW_SUM(v1);
    ROW_SUM(v2);

    // Score j = s+1 (valid iff j <= nb; nb >= 2 so j=1,2 always valid).
    float m = INFINITY;
    if (s < 12 && (s + 1) <= nb) {
        const float dot = fmaf(p0, v0, fmaf(p1, v1, p2 * v2));
        float q = p0 * p0 * gA.x;           // g00
        q = fmaf(p1 * p1, gA.w, q);         // g11
        q = fmaf(p2 * p2, gB.y, q);         // g22
        q = fmaf(2.0f * p0 * p1, gA.y, q);  // g01
        q = fmaf(2.0f * p0 * p2, gA.z, q);  // g02
        q = fmaf(2.0f * p1 * p2, gB.x, q);  // g12
        m = fmaf(-2.0f, dot, q);
    }
    float bm = m;
    ROW_MIN(bm);
    const unsigned long long mask = __ballot(m == bm);
    if (s == 0) {
        const int group = (threadIdx.x >> 4) & 3;
        const unsigned slice = (unsigned)((mask >> (group * 16)) & 0xffffu);
        const int jm1 = __builtin_ctz(slice);   // lane s ↔ j=s+1
        out[b] = (float)jm1 / (float)(nb - 1) + 1.0f;
    }
}

extern "C" void kernel_launch(void* const* d_in, const int* in_sizes, int n_in,
                              void* d_out, int out_size, void* d_ws, size_t ws_size,
                              hipStream_t stream) {
    const int*   user_ids    = (const int*)d_in[0];
    const int*   item_ids    = (const int*)d_in[1];
    const int*   concept_ids = (const int*)d_in[2];
    const float* users_emb   = (const float*)d_in[3];
    const float* item_resp   = (const float*)d_in[4];
    const float* W           = (const float*)d_in[5];
    // d_in[6] = mask: unused — validity recomputed from nb_modalities.
    const int*   nb_mod      = (const int*)d_in[7];
    float*       gram        = (float*)d_ws;   // 128*8 floats = 4 KB
    float*       out         = (float*)d_out;

    gram_kernel<<<dim3(128), dim3(64), 0, stream>>>(W, gram);
    impact_kernel<<<dim3(B_TOTAL / 16), dim3(256), 0, stream>>>(
        user_ids, item_ids, concept_ids, users_emb, item_resp, W, nb_mod,
        gram, out);
}